// Round 1
// baseline (360.822 us; speedup 1.0000x reference)
//
#include <hip/hip_runtime.h>
#include <stdint.h>

#define N_NODES 10000
#define N_EDGES 160000
#define D 512
#define TOT (N_NODES * D)          // 5,120,000
#define M_PAD 10112                // 79 * 128, GEMM M coverage
#define NMASK (TOT / 32)           // 160,000 u32 words per dropout mask

typedef _Float16 h8 __attribute__((ext_vector_type(8)));
typedef _Float16 h2 __attribute__((ext_vector_type(2)));
typedef float f4 __attribute__((ext_vector_type(4)));

// ---------------- threefry2x32 (JAX partitionable semantics) ----------------
__host__ __device__ inline uint32_t rotl32(uint32_t v, int r) {
    return (v << r) | (v >> (32 - r));
}

__host__ __device__ inline void tf2x32(uint32_t k0, uint32_t k1,
                                       uint32_t& x0, uint32_t& x1) {
    uint32_t k2 = k0 ^ k1 ^ 0x1BD11BDAu;
    x0 += k0; x1 += k1;
    x0 += x1; x1 = rotl32(x1, 13); x1 ^= x0;
    x0 += x1; x1 = rotl32(x1, 15); x1 ^= x0;
    x0 += x1; x1 = rotl32(x1, 26); x1 ^= x0;
    x0 += x1; x1 = rotl32(x1,  6); x1 ^= x0;
    x0 += k1; x1 += k2 + 1u;
    x0 += x1; x1 = rotl32(x1, 17); x1 ^= x0;
    x0 += x1; x1 = rotl32(x1, 29); x1 ^= x0;
    x0 += x1; x1 = rotl32(x1, 16); x1 ^= x0;
    x0 += x1; x1 = rotl32(x1, 24); x1 ^= x0;
    x0 += k2; x1 += k0 + 2u;
    x0 += x1; x1 = rotl32(x1, 13); x1 ^= x0;
    x0 += x1; x1 = rotl32(x1, 15); x1 ^= x0;
    x0 += x1; x1 = rotl32(x1, 26); x1 ^= x0;
    x0 += x1; x1 = rotl32(x1,  6); x1 ^= x0;
    x0 += k0; x1 += k1 + 3u;
    x0 += x1; x1 = rotl32(x1, 17); x1 ^= x0;
    x0 += x1; x1 = rotl32(x1, 29); x1 ^= x0;
    x0 += x1; x1 = rotl32(x1, 16); x1 ^= x0;
    x0 += x1; x1 = rotl32(x1, 24); x1 ^= x0;
    x0 += k1; x1 += k2 + 4u;
    x0 += x1; x1 = rotl32(x1, 13); x1 ^= x0;
    x0 += x1; x1 = rotl32(x1, 15); x1 ^= x0;
    x0 += x1; x1 = rotl32(x1, 26); x1 ^= x0;
    x0 += x1; x1 = rotl32(x1,  6); x1 ^= x0;
    x0 += k2; x1 += k0 + 5u;
}

__device__ __forceinline__ uint32_t dropout_bit(uint32_t k0, uint32_t k1, uint32_t j) {
    uint32_t c0 = 0u, c1 = j;
    tf2x32(k0, k1, c0, c1);
    uint32_t bits = c0 ^ c1;
    float u = __uint_as_float((bits >> 9) | 0x3f800000u) - 1.0f;
    return (u < 0.8f) ? 1u : 0u;
}

// ---------------- fused pre-pass: hist + W-transpose + dropout0 -------------
// block ranges: [0,625) hist, [625,817) wconvert, [817,5817) dropout layer 0.
// NOTE: dropout no longer applies rn_out (src-norm folded into edge weights).
#define HIST_BLKS 625
#define WCONV_BLKS 192
#define PRE_BLKS (HIST_BLKS + WCONV_BLKS + 5000)
__global__ __launch_bounds__(256)
void pre_kernel(const int* __restrict__ src, const int* __restrict__ dst,
                int* __restrict__ deg_out, int* __restrict__ deg_in,
                const float* __restrict__ W0, const float* __restrict__ W1,
                const float* __restrict__ W2, _Float16* __restrict__ Wt,
                const float* __restrict__ x, _Float16* __restrict__ y,
                uint32_t k0, uint32_t k1) {
    __shared__ float tile[64][65];
    int b = blockIdx.x;
    int t = threadIdx.x;
    if (b < HIST_BLKS) {
        int e = b * 256 + t;
        if (e < N_EDGES) {
            atomicAdd(&deg_out[src[e]], 1);
            atomicAdd(&deg_in[dst[e]], 1);
        }
    } else if (b < HIST_BLKS + WCONV_BLKS) {
        int b2 = b - HIST_BLKS;
        int bx = b2 & 7, by = (b2 >> 3) & 7, bz = b2 >> 6;
        const float* W = (bz == 0) ? W0 : (bz == 1) ? W1 : W2;
        _Float16* T = Wt + (size_t)bz * 512 * 512;
        int r0 = by * 64, c0 = bx * 64;
        int c = t & 63, rq = t >> 6;
#pragma unroll
        for (int i = 0; i < 16; ++i) {
            int r = rq + i * 4;
            tile[r][c] = W[(size_t)(r0 + r) * 512 + c0 + c];
        }
        __syncthreads();
        int k = t & 63, nq = t >> 6;
#pragma unroll
        for (int i = 0; i < 16; ++i) {
            int n = nq + i * 4;
            T[(size_t)(c0 + n) * 512 + r0 + k] = (_Float16)tile[k][n];
        }
    } else {
        int b3 = b - HIST_BLKS - WCONV_BLKS;
        int j = (b3 * 256 + t) * 4;
        if (j >= TOT) return;
        float4 xv = *(const float4*)&x[j];
        _Float16 r[4];
        uint32_t jj = (uint32_t)j;
#pragma unroll
        for (int i = 0; i < 4; ++i) {
            float g = dropout_bit(k0, k1, jj + (uint32_t)i) ? 1.0f : 0.0f;
            float xi = (&xv.x)[i];
            r[i] = (_Float16)(g * (xi / 0.8f));
        }
        *(ushort4*)&y[j] = *(ushort4*)r;
    }
}

// ---------------- single-pass scan: 1024 threads x 10 elems, 2 barriers -----
__global__ __launch_bounds__(1024)
void scan_kernel(const int* __restrict__ deg_in, const int* __restrict__ deg_out,
                 int* __restrict__ row_ptr,
                 float* __restrict__ rn_in, float* __restrict__ rn_out) {
    __shared__ int wsum[16];
    int tid = threadIdx.x;
    int lane = tid & 63, wv = tid >> 6;
    int base = tid * 10;
    int v[10];
    int tot = 0;
#pragma unroll
    for (int i = 0; i < 10; ++i) {
        int idx = base + i;
        v[i] = (idx < N_NODES) ? deg_in[idx] : 0;
        tot += v[i];
    }
    int s = tot;
#pragma unroll
    for (int off = 1; off < 64; off <<= 1) {
        int t = __shfl_up(s, off, 64);
        if (lane >= off) s += t;
    }
    if (lane == 63) wsum[wv] = s;
    __syncthreads();
    if (wv == 0 && lane < 16) {
        int ws = wsum[lane];
#pragma unroll
        for (int off = 1; off < 16; off <<= 1) {
            int t = __shfl_up(ws, off, 64);
            if (lane >= off) ws += t;
        }
        wsum[lane] = ws;
    }
    __syncthreads();
    int run = ((wv > 0) ? wsum[wv - 1] : 0) + (s - tot);
#pragma unroll
    for (int i = 0; i < 10; ++i) {
        int idx = base + i;
        if (idx < N_NODES) {
            row_ptr[idx] = run;
            rn_in[idx]  = 1.0f / sqrtf(fmaxf((float)v[i], 1.0f));
            rn_out[idx] = 1.0f / sqrtf(fmaxf((float)deg_out[idx], 1.0f));
        }
        run += v[i];
    }
    if (tid == 1023) row_ptr[N_NODES] = wsum[15];
}

// ---------------- CSR fill; edge weight pre-multiplied by rn_out[src] -------
__global__ void fill_kernel(const int* __restrict__ src, const int* __restrict__ dst,
                            const float* __restrict__ ew, const int* __restrict__ row_ptr,
                            const float* __restrict__ rn_out,
                            int* __restrict__ cursor, int2* __restrict__ csr) {
    int e = blockIdx.x * 256 + threadIdx.x;
    if (e >= N_EDGES) return;
    int v = dst[e];
    int sn = src[e];
    int pos = atomicAdd(&cursor[v], 1);
    int idx = row_ptr[v] + pos;
    csr[idx] = make_int2(sn, __float_as_int(ew[e] * rn_out[sn]));
}

// ---------------- aggregate: column-sliced for L2 residency -----------------
// blockIdx.y = slice (128 cols = 256B/row -> 2.56MB working set, fits 4MB L2).
// 1 wave per node per slice, 8-edge unroll, 4B/lane gathers.
// Slice-0 blocks additionally generate the next layer's dropout bitmask
// (threefry VALU work hidden under gather memory stalls).
__global__ __launch_bounds__(256)
void aggregate_kernel(const _Float16* __restrict__ y, const int* __restrict__ row_ptr,
                      const int2* __restrict__ csr, _Float16* __restrict__ agg,
                      uint32_t* __restrict__ mask, uint32_t mk0, uint32_t mk1) {
    int node = blockIdx.x * 4 + (threadIdx.x >> 6);
    int lane = threadIdx.x & 63;
    int cs = blockIdx.y;
    const _Float16* ys = y + cs * 128 + lane * 2;
    int beg = row_ptr[node], end = row_ptr[node + 1];
    float a0 = 0.f, a1 = 0.f;
    int k = beg;
    for (; k + 7 < end; k += 8) {
        int2 e[8];
#pragma unroll
        for (int i = 0; i < 8; ++i) e[i] = csr[k + i];
        h2 v[8];
#pragma unroll
        for (int i = 0; i < 8; ++i) v[i] = *(const h2*)&ys[(size_t)e[i].x * 512];
#pragma unroll
        for (int i = 0; i < 8; ++i) {
            float w = __int_as_float(e[i].y);
            a0 += w * (float)v[i][0];
            a1 += w * (float)v[i][1];
        }
    }
    for (; k < end; ++k) {
        int2 e0 = csr[k];
        float w = __int_as_float(e0.y);
        h2 v = *(const h2*)&ys[(size_t)e0.x * 512];
        a0 += w * (float)v[0];
        a1 += w * (float)v[1];
    }
    h2 r;
    r[0] = (_Float16)a0;
    r[1] = (_Float16)a1;
    *(h2*)&agg[(size_t)node * 512 + cs * 128 + lane * 2] = r;

    if (cs == 0 && mask) {
        int gtid = blockIdx.x * 256 + threadIdx.x;
        if (gtid < NMASK) {
            uint32_t w = 0, jb = (uint32_t)gtid * 32u;
#pragma unroll 4
            for (int i = 0; i < 32; ++i)
                w |= dropout_bit(mk0, mk1, jb + (uint32_t)i) << i;
            mask[gtid] = w;
        }
    }
}

// ---------------- fp16 MFMA GEMM, tile 128x128, BK=32, reg-staged pipeline --
// C[M,512] = A[M,512] @ Wt[512,512]^T  (Wt is [N][K])
// m97 structure: 2x2 waves, each 64x64 (4x4 16x16x32 tiles, 16 MFMA/K-step).
// LDS rows padded to 40 halves: start banks cycle over 8 rows -> 2-way-only
// aliasing on b128 reads/writes (free per m136). Register prefetch of tile
// k+1 issued right after barrier -> global latency overlaps ds_read+MFMA.
// Dropout in epilogue reads the precomputed bitmask (no threefry in tail).
#define GBK 32
#define LDA 40
__global__ __launch_bounds__(256)
void gemm_kernel(const _Float16* __restrict__ A, const _Float16* __restrict__ Wt,
                 const float* __restrict__ bias, const float* __restrict__ rn_in,
                 _Float16* __restrict__ yout, float* __restrict__ fout,
                 int mode, const uint32_t* __restrict__ mask) {
    __shared__ _Float16 As[128 * LDA];   // 10 KB
    __shared__ _Float16 Bs[128 * LDA];   // 10 KB
    int tid = threadIdx.x;
    int wv = tid >> 6, lane = tid & 63;

    // bijective XCD swizzle (m204): nwg=316, q=39, r=4
    int f = blockIdx.x + blockIdx.y * 4;
    int xcd = f & 7, jj = f >> 3;
    int T = ((xcd < 4) ? xcd * 40 : 160 + (xcd - 4) * 39) + jj;
    int row0 = (T >> 2) * 128, col0 = (T & 3) * 128;

    int wr = wv >> 1, wc = wv & 1;       // 2x2 wave grid: 64x64 each

    f4 acc[4][4];
#pragma unroll
    for (int i = 0; i < 4; ++i)
#pragma unroll
        for (int j = 0; j < 4; ++j) acc[i][j] = (f4){0.f, 0.f, 0.f, 0.f};

    // staging: A-tile 128x32 halves = 512 16B-chunks, 2/thread; B same
    int srow = tid >> 2;                 // 0..63
    int sseg = (tid & 3) * 8;            // k offset in halves
    const _Float16* gA0 = A + (size_t)(row0 + srow) * 512 + sseg;
    const _Float16* gA1 = gA0 + (size_t)64 * 512;
    const _Float16* gB0 = Wt + (size_t)(col0 + srow) * 512 + sseg;
    const _Float16* gB1 = gB0 + (size_t)64 * 512;
    _Float16* wA0 = &As[srow * LDA + sseg];
    _Float16* wA1 = &As[(64 + srow) * LDA + sseg];
    _Float16* wB0 = &Bs[srow * LDA + sseg];
    _Float16* wB1 = &Bs[(64 + srow) * LDA + sseg];

    int kf = (lane >> 4) * 8;            // k-chunk per quad
    const _Float16* fa = &As[(wr * 64 + (lane & 15)) * LDA + kf];
    const _Float16* fb = &Bs[(wc * 64 + (lane & 15)) * LDA + kf];

    h8 ra0 = *(const h8*)gA0;
    h8 ra1 = *(const h8*)gA1;
    h8 rb0 = *(const h8*)gB0;
    h8 rb1 = *(const h8*)gB1;

    for (int kk = 0; kk < 512; kk += GBK) {
        *(h8*)wA0 = ra0;
        *(h8*)wA1 = ra1;
        *(h8*)wB0 = rb0;
        *(h8*)wB1 = rb1;
        __syncthreads();
        if (kk + GBK < 512) {            // prefetch next tile into registers
            ra0 = *(const h8*)(gA0 + kk + GBK);
            ra1 = *(const h8*)(gA1 + kk + GBK);
            rb0 = *(const h8*)(gB0 + kk + GBK);
            rb1 = *(const h8*)(gB1 + kk + GBK);
        }
        h8 af[4], bf[4];
#pragma unroll
        for (int mt = 0; mt < 4; ++mt) af[mt] = *(const h8*)(fa + mt * 16 * LDA);
#pragma unroll
        for (int nt = 0; nt < 4; ++nt) bf[nt] = *(const h8*)(fb + nt * 16 * LDA);
#pragma unroll
        for (int mt = 0; mt < 4; ++mt)
#pragma unroll
            for (int nt = 0; nt < 4; ++nt)
                acc[mt][nt] = __builtin_amdgcn_mfma_f32_16x16x32_f16(
                    af[mt], bf[nt], acc[mt][nt], 0, 0, 0);
        __syncthreads();
    }

    // epilogue. C/D layout: col = lane&15, row = (lane>>4)*4 + reg
    int mbase = row0 + wr * 64;
    int nbase = col0 + wc * 64;
#pragma unroll
    for (int mt = 0; mt < 4; ++mt) {
#pragma unroll
        for (int nt = 0; nt < 4; ++nt) {
            int gr0 = mbase + mt * 16 + (lane >> 4) * 4;
            int gc = nbase + nt * 16 + (lane & 15);
            float bcol = bias[gc];
#pragma unroll
            for (int i = 0; i < 4; ++i) {
                int gr = gr0 + i;
                if (gr >= N_NODES) continue;
                float v = acc[mt][nt][i] * rn_in[gr] + bcol;
                if (mode == 0) {
                    v = (v > 0.f) ? v : expm1f(v);
                    uint32_t j = (uint32_t)(gr * 512 + gc);
                    uint32_t g = (mask[j >> 5] >> (j & 31)) & 1u;
                    v = g ? (v / 0.8f) : 0.0f;
                    yout[(size_t)gr * 512 + gc] = (_Float16)v;
                } else {
                    fout[(size_t)gr * 512 + gc] = v;
                }
            }
        }
    }
}

// ---------------- launch ----------------
extern "C" void kernel_launch(void* const* d_in, const int* in_sizes, int n_in,
                              void* d_out, int out_size, void* d_ws, size_t ws_size,
                              hipStream_t stream) {
    const float* h   = (const float*)d_in[0];
    const int*   src = (const int*)d_in[1];
    const int*   dst = (const int*)d_in[2];
    const float* ew  = (const float*)d_in[3];
    const float* W0  = (const float*)d_in[4];
    const float* b0  = (const float*)d_in[5];
    const float* W1  = (const float*)d_in[6];
    const float* b1  = (const float*)d_in[7];
    const float* W2  = (const float*)d_in[8];
    const float* b2  = (const float*)d_in[9];
    const float* bl[3] = {b0, b1, b2};
    float* out = (float*)d_out;

    char* ws = (char*)d_ws;
    _Float16* y16  = (_Float16*)ws; ws += (size_t)TOT * 2;            // 10.24 MB
    _Float16* aggF = (_Float16*)ws; ws += (size_t)M_PAD * 512 * 2;    // 10.35 MB
    _Float16* Wt   = (_Float16*)ws; ws += (size_t)3 * 512 * 512 * 2;  // 1.57 MB
    // the next three must stay contiguous: zeroed with ONE memset
    int* degi_in  = (int*)ws;  ws += N_NODES * 4;
    int* degi_out = (int*)ws;  ws += N_NODES * 4;
    int* cursor   = (int*)ws;  ws += N_NODES * 4;
    int* row_ptr  = (int*)ws;  ws += (N_NODES + 1) * 4;
    ws = (char*)(((uintptr_t)ws + 15) & ~(uintptr_t)15);
    int2* csr     = (int2*)ws; ws += (size_t)N_EDGES * 8;
    float* rn_in  = (float*)ws; ws += N_NODES * 4;
    float* rn_out = (float*)ws; ws += N_NODES * 4;
    uint32_t* maskbuf = (uint32_t*)ws; ws += (size_t)NMASK * 4;       // 640 KB

    hipMemsetAsync(degi_in, 0, 3 * N_NODES * 4, stream);

    // partitionable split: subkey i = both lanes of cipher(key=(0,42), x0=0, x1=i)
    uint32_t dk[3][2];
    for (int i = 0; i < 3; ++i) {
        uint32_t c0 = 0u, c1 = (uint32_t)i;
        tf2x32(0u, 42u, c0, c1);
        dk[i][0] = c0; dk[i][1] = c1;
    }

    pre_kernel<<<PRE_BLKS, 256, 0, stream>>>(src, dst, degi_out, degi_in,
                                             W0, W1, W2, Wt, h, y16,
                                             dk[0][0], dk[0][1]);
    scan_kernel<<<1, 1024, 0, stream>>>(degi_in, degi_out, row_ptr, rn_in, rn_out);
    fill_kernel<<<(N_EDGES + 255) / 256, 256, 0, stream>>>(src, dst, ew, row_ptr,
                                                           rn_out, cursor, csr);

    for (int l = 0; l < 3; ++l) {
        uint32_t* mk = (l < 2) ? maskbuf : nullptr;
        uint32_t mk0 = (l < 2) ? dk[l + 1][0] : 0u;
        uint32_t mk1 = (l < 2) ? dk[l + 1][1] : 0u;
        aggregate_kernel<<<dim3(N_NODES / 4, 4), 256, 0, stream>>>(
            y16, row_ptr, csr, aggF, mk, mk0, mk1);
        int mode = (l < 2) ? 0 : 1;
        gemm_kernel<<<dim3(4, M_PAD / 128), 256, 0, stream>>>(
            aggF, Wt + (size_t)l * 512 * 512, bl[l], rn_in,
            y16, out, mode, maskbuf);
    }
}

// Round 2
// 329.527 us; speedup vs baseline: 1.0950x; 1.0950x over previous
//
#include <hip/hip_runtime.h>
#include <stdint.h>

#define N_NODES 10000
#define N_EDGES 160000
#define D 512
#define TOT (N_NODES * D)          // 5,120,000
#define M_PAD 10112                // 158 * 64, GEMM M coverage
#define NMASK (TOT / 32)           // 160,000 u32 words per dropout mask

typedef _Float16 h8 __attribute__((ext_vector_type(8)));
typedef _Float16 h2 __attribute__((ext_vector_type(2)));
typedef float f4 __attribute__((ext_vector_type(4)));

// ---------------- threefry2x32 (JAX partitionable semantics) ----------------
__host__ __device__ inline uint32_t rotl32(uint32_t v, int r) {
    return (v << r) | (v >> (32 - r));
}

__host__ __device__ inline void tf2x32(uint32_t k0, uint32_t k1,
                                       uint32_t& x0, uint32_t& x1) {
    uint32_t k2 = k0 ^ k1 ^ 0x1BD11BDAu;
    x0 += k0; x1 += k1;
    x0 += x1; x1 = rotl32(x1, 13); x1 ^= x0;
    x0 += x1; x1 = rotl32(x1, 15); x1 ^= x0;
    x0 += x1; x1 = rotl32(x1, 26); x1 ^= x0;
    x0 += x1; x1 = rotl32(x1,  6); x1 ^= x0;
    x0 += k1; x1 += k2 + 1u;
    x0 += x1; x1 = rotl32(x1, 17); x1 ^= x0;
    x0 += x1; x1 = rotl32(x1, 29); x1 ^= x0;
    x0 += x1; x1 = rotl32(x1, 16); x1 ^= x0;
    x0 += x1; x1 = rotl32(x1, 24); x1 ^= x0;
    x0 += k2; x1 += k0 + 2u;
    x0 += x1; x1 = rotl32(x1, 13); x1 ^= x0;
    x0 += x1; x1 = rotl32(x1, 15); x1 ^= x0;
    x0 += x1; x1 = rotl32(x1, 26); x1 ^= x0;
    x0 += x1; x1 = rotl32(x1,  6); x1 ^= x0;
    x0 += k0; x1 += k1 + 3u;
    x0 += x1; x1 = rotl32(x1, 17); x1 ^= x0;
    x0 += x1; x1 = rotl32(x1, 29); x1 ^= x0;
    x0 += x1; x1 = rotl32(x1, 16); x1 ^= x0;
    x0 += x1; x1 = rotl32(x1, 24); x1 ^= x0;
    x0 += k1; x1 += k2 + 4u;
    x0 += x1; x1 = rotl32(x1, 13); x1 ^= x0;
    x0 += x1; x1 = rotl32(x1, 15); x1 ^= x0;
    x0 += x1; x1 = rotl32(x1, 26); x1 ^= x0;
    x0 += x1; x1 = rotl32(x1,  6); x1 ^= x0;
    x0 += k2; x1 += k0 + 5u;
}

__device__ __forceinline__ uint32_t dropout_bit(uint32_t k0, uint32_t k1, uint32_t j) {
    uint32_t c0 = 0u, c1 = j;
    tf2x32(k0, k1, c0, c1);
    uint32_t bits = c0 ^ c1;
    float u = __uint_as_float((bits >> 9) | 0x3f800000u) - 1.0f;
    return (u < 0.8f) ? 1u : 0u;
}

// ---------------- fused pre-pass: hist + W-transpose + dropout0 -------------
// block ranges: [0,625) hist, [625,817) wconvert, [817,5817) dropout layer 0.
// NOTE: dropout does not apply rn_out (src-norm folded into edge weights).
#define HIST_BLKS 625
#define WCONV_BLKS 192
#define PRE_BLKS (HIST_BLKS + WCONV_BLKS + 5000)
__global__ __launch_bounds__(256)
void pre_kernel(const int* __restrict__ src, const int* __restrict__ dst,
                int* __restrict__ deg_out, int* __restrict__ deg_in,
                const float* __restrict__ W0, const float* __restrict__ W1,
                const float* __restrict__ W2, _Float16* __restrict__ Wt,
                const float* __restrict__ x, _Float16* __restrict__ y,
                uint32_t k0, uint32_t k1) {
    __shared__ float tile[64][65];
    int b = blockIdx.x;
    int t = threadIdx.x;
    if (b < HIST_BLKS) {
        int e = b * 256 + t;
        if (e < N_EDGES) {
            atomicAdd(&deg_out[src[e]], 1);
            atomicAdd(&deg_in[dst[e]], 1);
        }
    } else if (b < HIST_BLKS + WCONV_BLKS) {
        int b2 = b - HIST_BLKS;
        int bx = b2 & 7, by = (b2 >> 3) & 7, bz = b2 >> 6;
        const float* W = (bz == 0) ? W0 : (bz == 1) ? W1 : W2;
        _Float16* T = Wt + (size_t)bz * 512 * 512;
        int r0 = by * 64, c0 = bx * 64;
        int c = t & 63, rq = t >> 6;
#pragma unroll
        for (int i = 0; i < 16; ++i) {
            int r = rq + i * 4;
            tile[r][c] = W[(size_t)(r0 + r) * 512 + c0 + c];
        }
        __syncthreads();
        int k = t & 63, nq = t >> 6;
#pragma unroll
        for (int i = 0; i < 16; ++i) {
            int n = nq + i * 4;
            T[(size_t)(c0 + n) * 512 + r0 + k] = (_Float16)tile[k][n];
        }
    } else {
        int b3 = b - HIST_BLKS - WCONV_BLKS;
        int j = (b3 * 256 + t) * 4;
        if (j >= TOT) return;
        float4 xv = *(const float4*)&x[j];
        _Float16 r[4];
        uint32_t jj = (uint32_t)j;
#pragma unroll
        for (int i = 0; i < 4; ++i) {
            float g = dropout_bit(k0, k1, jj + (uint32_t)i) ? 1.0f : 0.0f;
            float xi = (&xv.x)[i];
            r[i] = (_Float16)(g * (xi / 0.8f));
        }
        *(ushort4*)&y[j] = *(ushort4*)r;
    }
}

// ---------------- single-pass scan: 1024 threads x 10 elems, 2 barriers -----
__global__ __launch_bounds__(1024)
void scan_kernel(const int* __restrict__ deg_in, const int* __restrict__ deg_out,
                 int* __restrict__ row_ptr,
                 float* __restrict__ rn_in, float* __restrict__ rn_out) {
    __shared__ int wsum[16];
    int tid = threadIdx.x;
    int lane = tid & 63, wv = tid >> 6;
    int base = tid * 10;
    int v[10];
    int tot = 0;
#pragma unroll
    for (int i = 0; i < 10; ++i) {
        int idx = base + i;
        v[i] = (idx < N_NODES) ? deg_in[idx] : 0;
        tot += v[i];
    }
    int s = tot;
#pragma unroll
    for (int off = 1; off < 64; off <<= 1) {
        int t = __shfl_up(s, off, 64);
        if (lane >= off) s += t;
    }
    if (lane == 63) wsum[wv] = s;
    __syncthreads();
    if (wv == 0 && lane < 16) {
        int ws = wsum[lane];
#pragma unroll
        for (int off = 1; off < 16; off <<= 1) {
            int t = __shfl_up(ws, off, 64);
            if (lane >= off) ws += t;
        }
        wsum[lane] = ws;
    }
    __syncthreads();
    int run = ((wv > 0) ? wsum[wv - 1] : 0) + (s - tot);
#pragma unroll
    for (int i = 0; i < 10; ++i) {
        int idx = base + i;
        if (idx < N_NODES) {
            row_ptr[idx] = run;
            rn_in[idx]  = 1.0f / sqrtf(fmaxf((float)v[i], 1.0f));
            rn_out[idx] = 1.0f / sqrtf(fmaxf((float)deg_out[idx], 1.0f));
        }
        run += v[i];
    }
    if (tid == 1023) row_ptr[N_NODES] = wsum[15];
}

// ---------------- CSR fill; edge weight pre-multiplied by rn_out[src] -------
__global__ void fill_kernel(const int* __restrict__ src, const int* __restrict__ dst,
                            const float* __restrict__ ew, const int* __restrict__ row_ptr,
                            const float* __restrict__ rn_out,
                            int* __restrict__ cursor, int2* __restrict__ csr) {
    int e = blockIdx.x * 256 + threadIdx.x;
    if (e >= N_EDGES) return;
    int v = dst[e];
    int sn = src[e];
    int pos = atomicAdd(&cursor[v], 1);
    int idx = row_ptr[v] + pos;
    csr[idx] = make_int2(sn, __float_as_int(ew[e] * rn_out[sn]));
}

// ---------------- aggregate: column-sliced for L2 residency -----------------
// blockIdx.y = slice (128 cols = 256B/row -> 2.56MB working set, fits 4MB L2).
// Grid (2500, 4): linear id = bx + by*2500, so the concurrent dispatch window
// stays within one slice -> each XCD's L2 holds the active slice.
// Slice-0 blocks additionally generate the next layer's dropout bitmask
// (threefry VALU work hidden under gather memory stalls).
__global__ __launch_bounds__(256)
void aggregate_kernel(const _Float16* __restrict__ y, const int* __restrict__ row_ptr,
                      const int2* __restrict__ csr, _Float16* __restrict__ agg,
                      uint32_t* __restrict__ mask, uint32_t mk0, uint32_t mk1) {
    int node = blockIdx.x * 4 + (threadIdx.x >> 6);
    int lane = threadIdx.x & 63;
    int cs = blockIdx.y;
    const _Float16* ys = y + cs * 128 + lane * 2;
    int beg = row_ptr[node], end = row_ptr[node + 1];
    float a0 = 0.f, a1 = 0.f;
    int k = beg;
    for (; k + 7 < end; k += 8) {
        int2 e[8];
#pragma unroll
        for (int i = 0; i < 8; ++i) e[i] = csr[k + i];
        h2 v[8];
#pragma unroll
        for (int i = 0; i < 8; ++i) v[i] = *(const h2*)&ys[(size_t)e[i].x * 512];
#pragma unroll
        for (int i = 0; i < 8; ++i) {
            float w = __int_as_float(e[i].y);
            a0 += w * (float)v[i][0];
            a1 += w * (float)v[i][1];
        }
    }
    for (; k < end; ++k) {
        int2 e0 = csr[k];
        float w = __int_as_float(e0.y);
        h2 v = *(const h2*)&ys[(size_t)e0.x * 512];
        a0 += w * (float)v[0];
        a1 += w * (float)v[1];
    }
    h2 r;
    r[0] = (_Float16)a0;
    r[1] = (_Float16)a1;
    *(h2*)&agg[(size_t)node * 512 + cs * 128 + lane * 2] = r;

    if (cs == 0 && mask) {
        int gtid = blockIdx.x * 256 + threadIdx.x;
        if (gtid < NMASK) {
            uint32_t w = 0, jb = (uint32_t)gtid * 32u;
#pragma unroll 4
            for (int i = 0; i < 32; ++i)
                w |= dropout_bit(mk0, mk1, jb + (uint32_t)i) << i;
            mask[gtid] = w;
        }
    }
}

// ---------------- fp16 MFMA GEMM, tile 64x64, BK=128: latency-bound regime --
// C[M,512] = A[M,512] @ Wt[512,512]^T  (Wt is [N][K])
// K=512 is SHORT: the old 128x128/BK=32 version ran 16 K-steps x 2 barriers
// with 316 blocks (~1.2/CU) -> MfmaUtil 4%, 45.8us (pure vmcnt-drain stall).
// This version: 4 K-steps only (BK=128) and 1264 blocks (~4 resident/CU,
// LDS 34KB) so other blocks' MFMA fills each block's barrier drains.
// LDS row stride 136 halves (272B = 68 words = 4 mod 32 banks): fragment
// reads AND staging writes land exactly 8 words/bank -> conflict-free b128.
#define GBK 128
#define LDA2 136
__global__ __launch_bounds__(256)
void gemm_kernel(const _Float16* __restrict__ A, const _Float16* __restrict__ Wt,
                 const float* __restrict__ bias, const float* __restrict__ rn_in,
                 _Float16* __restrict__ yout, float* __restrict__ fout,
                 int mode, const uint32_t* __restrict__ mask) {
    __shared__ _Float16 As[64 * LDA2];   // 17 KB
    __shared__ _Float16 Bs[64 * LDA2];   // 17 KB
    int tid = threadIdx.x;
    int wv = tid >> 6, lane = tid & 63;

    // XCD swizzle: nwg = 1264 = 158*8 (divisible by 8 -> simple form is
    // bijective). Each XCD owns a contiguous tile range -> its A row-slabs
    // stay L2-resident across the 8 column strips.
    int f = blockIdx.x;
    int T = (f & 7) * 158 + (f >> 3);
    int row0 = (T >> 3) * 64, col0 = (T & 7) * 64;

    int wr = wv >> 1, wc = wv & 1;       // 2x2 wave grid: 32x32 out each

    f4 acc[2][2];
#pragma unroll
    for (int i = 0; i < 2; ++i)
#pragma unroll
        for (int j = 0; j < 2; ++j) acc[i][j] = (f4){0.f, 0.f, 0.f, 0.f};

    // staging: A-tile 64x128 halves = 1024 16B-chunks, 4/thread; B same
    int r = tid >> 2;                    // 0..63
    int cseg = (tid & 3) * 32;           // halves base; +i*8, i=0..3
    const _Float16* gA = A  + (size_t)(row0 + r) * 512 + cseg;
    const _Float16* gB = Wt + (size_t)(col0 + r) * 512 + cseg;
    _Float16* wA = &As[r * LDA2 + cseg];
    _Float16* wB = &Bs[r * LDA2 + cseg];

    const _Float16* fa = &As[(wr * 32 + (lane & 15)) * LDA2 + (lane >> 4) * 8];
    const _Float16* fb = &Bs[(wc * 32 + (lane & 15)) * LDA2 + (lane >> 4) * 8];

    h8 ra[4], rb[4];
#pragma unroll
    for (int i = 0; i < 4; ++i) {
        ra[i] = *(const h8*)(gA + i * 8);
        rb[i] = *(const h8*)(gB + i * 8);
    }

    for (int kk = 0; kk < 512; kk += GBK) {
#pragma unroll
        for (int i = 0; i < 4; ++i) {
            *(h8*)(wA + i * 8) = ra[i];
            *(h8*)(wB + i * 8) = rb[i];
        }
        __syncthreads();
        if (kk + GBK < 512) {            // prefetch next tile into registers
#pragma unroll
            for (int i = 0; i < 4; ++i) {
                ra[i] = *(const h8*)(gA + kk + GBK + i * 8);
                rb[i] = *(const h8*)(gB + kk + GBK + i * 8);
            }
        }
#pragma unroll
        for (int s = 0; s < 4; ++s) {    // four K=32 slices within BK=128
            h8 af0 = *(const h8*)(fa + s * 32);
            h8 af1 = *(const h8*)(fa + 16 * LDA2 + s * 32);
            h8 bf0 = *(const h8*)(fb + s * 32);
            h8 bf1 = *(const h8*)(fb + 16 * LDA2 + s * 32);
            acc[0][0] = __builtin_amdgcn_mfma_f32_16x16x32_f16(af0, bf0, acc[0][0], 0, 0, 0);
            acc[0][1] = __builtin_amdgcn_mfma_f32_16x16x32_f16(af0, bf1, acc[0][1], 0, 0, 0);
            acc[1][0] = __builtin_amdgcn_mfma_f32_16x16x32_f16(af1, bf0, acc[1][0], 0, 0, 0);
            acc[1][1] = __builtin_amdgcn_mfma_f32_16x16x32_f16(af1, bf1, acc[1][1], 0, 0, 0);
        }
        __syncthreads();
    }

    // epilogue. C/D layout: col = lane&15, row = (lane>>4)*4 + reg
    int mbase = row0 + wr * 32;
    int nbase = col0 + wc * 32;
#pragma unroll
    for (int mt = 0; mt < 2; ++mt) {
#pragma unroll
        for (int nt = 0; nt < 2; ++nt) {
            int gr0 = mbase + mt * 16 + (lane >> 4) * 4;
            int gc = nbase + nt * 16 + (lane & 15);
            float bcol = bias[gc];
#pragma unroll
            for (int i = 0; i < 4; ++i) {
                int gr = gr0 + i;
                if (gr >= N_NODES) continue;
                float v = acc[mt][nt][i] * rn_in[gr] + bcol;
                if (mode == 0) {
                    v = (v > 0.f) ? v : expm1f(v);
                    uint32_t j = (uint32_t)(gr * 512 + gc);
                    uint32_t g = (mask[j >> 5] >> (j & 31)) & 1u;
                    v = g ? (v / 0.8f) : 0.0f;
                    yout[(size_t)gr * 512 + gc] = (_Float16)v;
                } else {
                    fout[(size_t)gr * 512 + gc] = v;
                }
            }
        }
    }
}

// ---------------- launch ----------------
extern "C" void kernel_launch(void* const* d_in, const int* in_sizes, int n_in,
                              void* d_out, int out_size, void* d_ws, size_t ws_size,
                              hipStream_t stream) {
    const float* h   = (const float*)d_in[0];
    const int*   src = (const int*)d_in[1];
    const int*   dst = (const int*)d_in[2];
    const float* ew  = (const float*)d_in[3];
    const float* W0  = (const float*)d_in[4];
    const float* b0  = (const float*)d_in[5];
    const float* W1  = (const float*)d_in[6];
    const float* b1  = (const float*)d_in[7];
    const float* W2  = (const float*)d_in[8];
    const float* b2  = (const float*)d_in[9];
    const float* bl[3] = {b0, b1, b2};
    float* out = (float*)d_out;

    char* ws = (char*)d_ws;
    _Float16* y16  = (_Float16*)ws; ws += (size_t)TOT * 2;            // 10.24 MB
    _Float16* aggF = (_Float16*)ws; ws += (size_t)M_PAD * 512 * 2;    // 10.35 MB
    _Float16* Wt   = (_Float16*)ws; ws += (size_t)3 * 512 * 512 * 2;  // 1.57 MB
    // the next three must stay contiguous: zeroed with ONE memset
    int* degi_in  = (int*)ws;  ws += N_NODES * 4;
    int* degi_out = (int*)ws;  ws += N_NODES * 4;
    int* cursor   = (int*)ws;  ws += N_NODES * 4;
    int* row_ptr  = (int*)ws;  ws += (N_NODES + 1) * 4;
    ws = (char*)(((uintptr_t)ws + 15) & ~(uintptr_t)15);
    int2* csr     = (int2*)ws; ws += (size_t)N_EDGES * 8;
    float* rn_in  = (float*)ws; ws += N_NODES * 4;
    float* rn_out = (float*)ws; ws += N_NODES * 4;
    uint32_t* maskbuf = (uint32_t*)ws; ws += (size_t)NMASK * 4;       // 640 KB

    hipMemsetAsync(degi_in, 0, 3 * N_NODES * 4, stream);

    // partitionable split: subkey i = both lanes of cipher(key=(0,42), x0=0, x1=i)
    uint32_t dk[3][2];
    for (int i = 0; i < 3; ++i) {
        uint32_t c0 = 0u, c1 = (uint32_t)i;
        tf2x32(0u, 42u, c0, c1);
        dk[i][0] = c0; dk[i][1] = c1;
    }

    pre_kernel<<<PRE_BLKS, 256, 0, stream>>>(src, dst, degi_out, degi_in,
                                             W0, W1, W2, Wt, h, y16,
                                             dk[0][0], dk[0][1]);
    scan_kernel<<<1, 1024, 0, stream>>>(degi_in, degi_out, row_ptr, rn_in, rn_out);
    fill_kernel<<<(N_EDGES + 255) / 256, 256, 0, stream>>>(src, dst, ew, row_ptr,
                                                           rn_out, cursor, csr);

    for (int l = 0; l < 3; ++l) {
        uint32_t* mk = (l < 2) ? maskbuf : nullptr;
        uint32_t mk0 = (l < 2) ? dk[l + 1][0] : 0u;
        uint32_t mk1 = (l < 2) ? dk[l + 1][1] : 0u;
        aggregate_kernel<<<dim3(N_NODES / 4, 4), 256, 0, stream>>>(
            y16, row_ptr, csr, aggF, mk, mk0, mk1);
        int mode = (l < 2) ? 0 : 1;
        gemm_kernel<<<1264, 256, 0, stream>>>(
            aggF, Wt + (size_t)l * 512 * 512, bl[l], rn_in,
            y16, out, mode, maskbuf);
    }
}

// Round 3
// 316.306 us; speedup vs baseline: 1.1407x; 1.0418x over previous
//
#include <hip/hip_runtime.h>
#include <stdint.h>

#define N_NODES 10000
#define N_EDGES 160000
#define D 512
#define TOT (N_NODES * D)          // 5,120,000
#define M_PAD 10112                // 158 * 64, GEMM M coverage
#define NMASK (TOT / 32)           // 160,000 u32 words per dropout mask
#define AGG_BLKS 2500
#define MASK_BLKS 625              // NMASK / 256

typedef _Float16 h8 __attribute__((ext_vector_type(8)));
typedef float f4 __attribute__((ext_vector_type(4)));

// ---------------- threefry2x32 (JAX partitionable semantics) ----------------
__host__ __device__ inline uint32_t rotl32(uint32_t v, int r) {
    return (v << r) | (v >> (32 - r));
}

__host__ __device__ inline void tf2x32(uint32_t k0, uint32_t k1,
                                       uint32_t& x0, uint32_t& x1) {
    uint32_t k2 = k0 ^ k1 ^ 0x1BD11BDAu;
    x0 += k0; x1 += k1;
    x0 += x1; x1 = rotl32(x1, 13); x1 ^= x0;
    x0 += x1; x1 = rotl32(x1, 15); x1 ^= x0;
    x0 += x1; x1 = rotl32(x1, 26); x1 ^= x0;
    x0 += x1; x1 = rotl32(x1,  6); x1 ^= x0;
    x0 += k1; x1 += k2 + 1u;
    x0 += x1; x1 = rotl32(x1, 17); x1 ^= x0;
    x0 += x1; x1 = rotl32(x1, 29); x1 ^= x0;
    x0 += x1; x1 = rotl32(x1, 16); x1 ^= x0;
    x0 += x1; x1 = rotl32(x1, 24); x1 ^= x0;
    x0 += k2; x1 += k0 + 2u;
    x0 += x1; x1 = rotl32(x1, 13); x1 ^= x0;
    x0 += x1; x1 = rotl32(x1, 15); x1 ^= x0;
    x0 += x1; x1 = rotl32(x1, 26); x1 ^= x0;
    x0 += x1; x1 = rotl32(x1,  6); x1 ^= x0;
    x0 += k0; x1 += k1 + 3u;
    x0 += x1; x1 = rotl32(x1, 17); x1 ^= x0;
    x0 += x1; x1 = rotl32(x1, 29); x1 ^= x0;
    x0 += x1; x1 = rotl32(x1, 16); x1 ^= x0;
    x0 += x1; x1 = rotl32(x1, 24); x1 ^= x0;
    x0 += k1; x1 += k2 + 4u;
    x0 += x1; x1 = rotl32(x1, 13); x1 ^= x0;
    x0 += x1; x1 = rotl32(x1, 15); x1 ^= x0;
    x0 += x1; x1 = rotl32(x1, 26); x1 ^= x0;
    x0 += x1; x1 = rotl32(x1,  6); x1 ^= x0;
    x0 += k2; x1 += k0 + 5u;
}

__device__ __forceinline__ uint32_t dropout_bit(uint32_t k0, uint32_t k1, uint32_t j) {
    uint32_t c0 = 0u, c1 = j;
    tf2x32(k0, k1, c0, c1);
    uint32_t bits = c0 ^ c1;
    float u = __uint_as_float((bits >> 9) | 0x3f800000u) - 1.0f;
    return (u < 0.8f) ? 1u : 0u;
}

// ---------------- fused pre-pass: hist + W-transpose + dropout0 -------------
// block ranges: [0,625) hist, [625,817) wconvert, [817,5817) dropout layer 0.
// NOTE: dropout does not apply rn_out (src-norm folded into edge weights).
#define HIST_BLKS 625
#define WCONV_BLKS 192
#define PRE_BLKS (HIST_BLKS + WCONV_BLKS + 5000)
__global__ __launch_bounds__(256)
void pre_kernel(const int* __restrict__ src, const int* __restrict__ dst,
                int* __restrict__ deg_out, int* __restrict__ deg_in,
                const float* __restrict__ W0, const float* __restrict__ W1,
                const float* __restrict__ W2, _Float16* __restrict__ Wt,
                const float* __restrict__ x, _Float16* __restrict__ y,
                uint32_t k0, uint32_t k1) {
    __shared__ float tile[64][65];
    int b = blockIdx.x;
    int t = threadIdx.x;
    if (b < HIST_BLKS) {
        int e = b * 256 + t;
        if (e < N_EDGES) {
            atomicAdd(&deg_out[src[e]], 1);
            atomicAdd(&deg_in[dst[e]], 1);
        }
    } else if (b < HIST_BLKS + WCONV_BLKS) {
        int b2 = b - HIST_BLKS;
        int bx = b2 & 7, by = (b2 >> 3) & 7, bz = b2 >> 6;
        const float* W = (bz == 0) ? W0 : (bz == 1) ? W1 : W2;
        _Float16* T = Wt + (size_t)bz * 512 * 512;
        int r0 = by * 64, c0 = bx * 64;
        int c = t & 63, rq = t >> 6;
#pragma unroll
        for (int i = 0; i < 16; ++i) {
            int r = rq + i * 4;
            tile[r][c] = W[(size_t)(r0 + r) * 512 + c0 + c];
        }
        __syncthreads();
        int k = t & 63, nq = t >> 6;
#pragma unroll
        for (int i = 0; i < 16; ++i) {
            int n = nq + i * 4;
            T[(size_t)(c0 + n) * 512 + r0 + k] = (_Float16)tile[k][n];
        }
    } else {
        int b3 = b - HIST_BLKS - WCONV_BLKS;
        int j = (b3 * 256 + t) * 4;
        if (j >= TOT) return;
        float4 xv = *(const float4*)&x[j];
        _Float16 r[4];
        uint32_t jj = (uint32_t)j;
#pragma unroll
        for (int i = 0; i < 4; ++i) {
            float g = dropout_bit(k0, k1, jj + (uint32_t)i) ? 1.0f : 0.0f;
            float xi = (&xv.x)[i];
            r[i] = (_Float16)(g * (xi * 1.25f));
        }
        *(ushort4*)&y[j] = *(ushort4*)r;
    }
}

// ---------------- single-pass scan: 1024 threads x 10 elems, 2 barriers -----
__global__ __launch_bounds__(1024)
void scan_kernel(const int* __restrict__ deg_in, const int* __restrict__ deg_out,
                 int* __restrict__ row_ptr,
                 float* __restrict__ rn_in, float* __restrict__ rn_out) {
    __shared__ int wsum[16];
    int tid = threadIdx.x;
    int lane = tid & 63, wv = tid >> 6;
    int base = tid * 10;
    int v[10];
    int tot = 0;
#pragma unroll
    for (int i = 0; i < 10; ++i) {
        int idx = base + i;
        v[i] = (idx < N_NODES) ? deg_in[idx] : 0;
        tot += v[i];
    }
    int s = tot;
#pragma unroll
    for (int off = 1; off < 64; off <<= 1) {
        int t = __shfl_up(s, off, 64);
        if (lane >= off) s += t;
    }
    if (lane == 63) wsum[wv] = s;
    __syncthreads();
    if (wv == 0 && lane < 16) {
        int ws = wsum[lane];
#pragma unroll
        for (int off = 1; off < 16; off <<= 1) {
            int t = __shfl_up(ws, off, 64);
            if (lane >= off) ws += t;
        }
        wsum[lane] = ws;
    }
    __syncthreads();
    int run = ((wv > 0) ? wsum[wv - 1] : 0) + (s - tot);
#pragma unroll
    for (int i = 0; i < 10; ++i) {
        int idx = base + i;
        if (idx < N_NODES) {
            row_ptr[idx] = run;
            rn_in[idx]  = 1.0f / sqrtf(fmaxf((float)v[i], 1.0f));
            rn_out[idx] = 1.0f / sqrtf(fmaxf((float)deg_out[idx], 1.0f));
        }
        run += v[i];
    }
    if (tid == 1023) row_ptr[N_NODES] = wsum[15];
}

// ---------------- CSR fill; edge weight pre-multiplied by rn_out[src] -------
__global__ void fill_kernel(const int* __restrict__ src, const int* __restrict__ dst,
                            const float* __restrict__ ew, const int* __restrict__ row_ptr,
                            const float* __restrict__ rn_out,
                            int* __restrict__ cursor, int2* __restrict__ csr) {
    int e = blockIdx.x * 256 + threadIdx.x;
    if (e >= N_EDGES) return;
    int v = dst[e];
    int sn = src[e];
    int pos = atomicAdd(&cursor[v], 1);
    int idx = row_ptr[v] + pos;
    csr[idx] = make_int2(sn, __float_as_int(ew[e] * rn_out[sn]));
}

// ---------------- aggregate: full-row h8 gather, 1 wave per node ------------
// 16 B/lane per edge (whole 1KB row per wave-load), 8-edge unroll for
// outstanding-load depth. Blocks [AGG_BLKS, AGG_BLKS+MASK_BLKS) generate the
// next layer's dropout bitmask instead (threefry runs in the aggregate tail).
__global__ __launch_bounds__(256)
void aggregate_kernel(const _Float16* __restrict__ y, const int* __restrict__ row_ptr,
                      const int2* __restrict__ csr, _Float16* __restrict__ agg,
                      uint32_t* __restrict__ mask, uint32_t mk0, uint32_t mk1) {
    int b = blockIdx.x;
    if (b >= AGG_BLKS) {                 // ---- mask-generation blocks ----
        if (mask == nullptr) return;
        int gtid = (b - AGG_BLKS) * 256 + threadIdx.x;
        if (gtid < NMASK) {
            uint32_t w = 0, jb = (uint32_t)gtid * 32u;
#pragma unroll 4
            for (int i = 0; i < 32; ++i)
                w |= dropout_bit(mk0, mk1, jb + (uint32_t)i) << i;
            mask[gtid] = w;
        }
        return;
    }
    int node = b * 4 + (threadIdx.x >> 6);
    int lane = threadIdx.x & 63;
    int beg = row_ptr[node], end = row_ptr[node + 1];
    const _Float16* yl = y + lane * 8;
    float acc[8] = {0, 0, 0, 0, 0, 0, 0, 0};
    int k = beg;
    for (; k + 7 < end; k += 8) {
        int2 e[8];
#pragma unroll
        for (int i = 0; i < 8; ++i) e[i] = csr[k + i];
        h8 v[8];
#pragma unroll
        for (int i = 0; i < 8; ++i) v[i] = *(const h8*)&yl[(size_t)e[i].x * 512];
#pragma unroll
        for (int i = 0; i < 8; ++i) {
            float w = __int_as_float(e[i].y);
#pragma unroll
            for (int j = 0; j < 8; ++j) acc[j] += w * (float)v[i][j];
        }
    }
    for (; k < end; ++k) {
        int2 e0 = csr[k];
        float w = __int_as_float(e0.y);
        h8 v = *(const h8*)&yl[(size_t)e0.x * 512];
#pragma unroll
        for (int j = 0; j < 8; ++j) acc[j] += w * (float)v[j];
    }
    _Float16 r[8];
#pragma unroll
    for (int j = 0; j < 8; ++j) r[j] = (_Float16)acc[j];
    *(h8*)&agg[(size_t)node * 512 + lane * 8] = *(h8*)r;
}

// ---------------- fp16 MFMA GEMM, tile 64x64, BK=128: latency-bound regime --
// C[M,512] = A[M,512] @ Wt[512,512]^T  (Wt is [N][K])
// 4 K-steps (BK=128), 1264 blocks (~4 resident/CU, LDS 34KB) so other
// blocks' MFMA fills each block's barrier drains.
// LDS row stride 136 halves (272B = 68 words = 4 mod 32 banks): fragment
// reads AND staging writes land exactly 8 words/bank -> conflict-free b128.
// ELU via v_exp_f32 (__expf), not libm expm1f: epilogue VALU ~10x cheaper.
#define GBK 128
#define LDA2 136
__global__ __launch_bounds__(256)
void gemm_kernel(const _Float16* __restrict__ A, const _Float16* __restrict__ Wt,
                 const float* __restrict__ bias, const float* __restrict__ rn_in,
                 _Float16* __restrict__ yout, float* __restrict__ fout,
                 int mode, const uint32_t* __restrict__ mask) {
    __shared__ _Float16 As[64 * LDA2];   // 17 KB
    __shared__ _Float16 Bs[64 * LDA2];   // 17 KB
    int tid = threadIdx.x;
    int wv = tid >> 6, lane = tid & 63;

    // XCD swizzle: nwg = 1264 = 158*8 (divisible by 8 -> simple form is
    // bijective). Each XCD owns a contiguous tile range -> its A row-slabs
    // stay L2-resident across the 8 column strips.
    int f = blockIdx.x;
    int T = (f & 7) * 158 + (f >> 3);
    int row0 = (T >> 3) * 64, col0 = (T & 7) * 64;

    int wr = wv >> 1, wc = wv & 1;       // 2x2 wave grid: 32x32 out each

    f4 acc[2][2];
#pragma unroll
    for (int i = 0; i < 2; ++i)
#pragma unroll
        for (int j = 0; j < 2; ++j) acc[i][j] = (f4){0.f, 0.f, 0.f, 0.f};

    // staging: A-tile 64x128 halves = 1024 16B-chunks, 4/thread; B same
    int r = tid >> 2;                    // 0..63
    int cseg = (tid & 3) * 32;           // halves base; +i*8, i=0..3
    const _Float16* gA = A  + (size_t)(row0 + r) * 512 + cseg;
    const _Float16* gB = Wt + (size_t)(col0 + r) * 512 + cseg;
    _Float16* wA = &As[r * LDA2 + cseg];
    _Float16* wB = &Bs[r * LDA2 + cseg];

    const _Float16* fa = &As[(wr * 32 + (lane & 15)) * LDA2 + (lane >> 4) * 8];
    const _Float16* fb = &Bs[(wc * 32 + (lane & 15)) * LDA2 + (lane >> 4) * 8];

    h8 ra[4], rb[4];
#pragma unroll
    for (int i = 0; i < 4; ++i) {
        ra[i] = *(const h8*)(gA + i * 8);
        rb[i] = *(const h8*)(gB + i * 8);
    }

    for (int kk = 0; kk < 512; kk += GBK) {
#pragma unroll
        for (int i = 0; i < 4; ++i) {
            *(h8*)(wA + i * 8) = ra[i];
            *(h8*)(wB + i * 8) = rb[i];
        }
        __syncthreads();
        if (kk + GBK < 512) {            // prefetch next tile into registers
#pragma unroll
            for (int i = 0; i < 4; ++i) {
                ra[i] = *(const h8*)(gA + kk + GBK + i * 8);
                rb[i] = *(const h8*)(gB + kk + GBK + i * 8);
            }
        }
#pragma unroll
        for (int s = 0; s < 4; ++s) {    // four K=32 slices within BK=128
            h8 af0 = *(const h8*)(fa + s * 32);
            h8 af1 = *(const h8*)(fa + 16 * LDA2 + s * 32);
            h8 bf0 = *(const h8*)(fb + s * 32);
            h8 bf1 = *(const h8*)(fb + 16 * LDA2 + s * 32);
            acc[0][0] = __builtin_amdgcn_mfma_f32_16x16x32_f16(af0, bf0, acc[0][0], 0, 0, 0);
            acc[0][1] = __builtin_amdgcn_mfma_f32_16x16x32_f16(af0, bf1, acc[0][1], 0, 0, 0);
            acc[1][0] = __builtin_amdgcn_mfma_f32_16x16x32_f16(af1, bf0, acc[1][0], 0, 0, 0);
            acc[1][1] = __builtin_amdgcn_mfma_f32_16x16x32_f16(af1, bf1, acc[1][1], 0, 0, 0);
        }
        __syncthreads();
    }

    // epilogue. C/D layout: col = lane&15, row = (lane>>4)*4 + reg
    int mbase = row0 + wr * 32;
    int nbase = col0 + wc * 32;
#pragma unroll
    for (int mt = 0; mt < 2; ++mt) {
#pragma unroll
        for (int nt = 0; nt < 2; ++nt) {
            int gr0 = mbase + mt * 16 + (lane >> 4) * 4;
            int gc = nbase + nt * 16 + (lane & 15);
            float bcol = bias[gc];
#pragma unroll
            for (int i = 0; i < 4; ++i) {
                int gr = gr0 + i;
                if (gr >= N_NODES) continue;
                float v = acc[mt][nt][i] * rn_in[gr] + bcol;
                if (mode == 0) {
                    // ELU: expm1(v) == exp(v)-1; v_exp_f32 error ~1e-8,
                    // invisible under fp16 output rounding.
                    v = (v > 0.f) ? v : (__expf(v) - 1.0f);
                    uint32_t j = (uint32_t)(gr * 512 + gc);
                    uint32_t g = (mask[j >> 5] >> (j & 31)) & 1u;
                    v = g ? (v * 1.25f) : 0.0f;
                    yout[(size_t)gr * 512 + gc] = (_Float16)v;
                } else {
                    fout[(size_t)gr * 512 + gc] = v;
                }
            }
        }
    }
}

// ---------------- launch ----------------
extern "C" void kernel_launch(void* const* d_in, const int* in_sizes, int n_in,
                              void* d_out, int out_size, void* d_ws, size_t ws_size,
                              hipStream_t stream) {
    const float* h   = (const float*)d_in[0];
    const int*   src = (const int*)d_in[1];
    const int*   dst = (const int*)d_in[2];
    const float* ew  = (const float*)d_in[3];
    const float* W0  = (const float*)d_in[4];
    const float* b0  = (const float*)d_in[5];
    const float* W1  = (const float*)d_in[6];
    const float* b1  = (const float*)d_in[7];
    const float* W2  = (const float*)d_in[8];
    const float* b2  = (const float*)d_in[9];
    const float* bl[3] = {b0, b1, b2};
    float* out = (float*)d_out;

    char* ws = (char*)d_ws;
    _Float16* y16  = (_Float16*)ws; ws += (size_t)TOT * 2;            // 10.24 MB
    _Float16* aggF = (_Float16*)ws; ws += (size_t)M_PAD * 512 * 2;    // 10.35 MB
    _Float16* Wt   = (_Float16*)ws; ws += (size_t)3 * 512 * 512 * 2;  // 1.57 MB
    // the next three must stay contiguous: zeroed with ONE memset
    int* degi_in  = (int*)ws;  ws += N_NODES * 4;
    int* degi_out = (int*)ws;  ws += N_NODES * 4;
    int* cursor   = (int*)ws;  ws += N_NODES * 4;
    int* row_ptr  = (int*)ws;  ws += (N_NODES + 1) * 4;
    ws = (char*)(((uintptr_t)ws + 15) & ~(uintptr_t)15);
    int2* csr     = (int2*)ws; ws += (size_t)N_EDGES * 8;
    float* rn_in  = (float*)ws; ws += N_NODES * 4;
    float* rn_out = (float*)ws; ws += N_NODES * 4;
    uint32_t* maskbuf = (uint32_t*)ws; ws += (size_t)NMASK * 4;       // 640 KB

    hipMemsetAsync(degi_in, 0, 3 * N_NODES * 4, stream);

    // partitionable split: subkey i = both lanes of cipher(key=(0,42), x0=0, x1=i)
    uint32_t dk[3][2];
    for (int i = 0; i < 3; ++i) {
        uint32_t c0 = 0u, c1 = (uint32_t)i;
        tf2x32(0u, 42u, c0, c1);
        dk[i][0] = c0; dk[i][1] = c1;
    }

    pre_kernel<<<PRE_BLKS, 256, 0, stream>>>(src, dst, degi_out, degi_in,
                                             W0, W1, W2, Wt, h, y16,
                                             dk[0][0], dk[0][1]);
    scan_kernel<<<1, 1024, 0, stream>>>(degi_in, degi_out, row_ptr, rn_in, rn_out);
    fill_kernel<<<(N_EDGES + 255) / 256, 256, 0, stream>>>(src, dst, ew, row_ptr,
                                                           rn_out, cursor, csr);

    for (int l = 0; l < 3; ++l) {
        uint32_t* mk = (l < 2) ? maskbuf : nullptr;
        uint32_t mk0 = (l < 2) ? dk[l + 1][0] : 0u;
        uint32_t mk1 = (l < 2) ? dk[l + 1][1] : 0u;
        aggregate_kernel<<<AGG_BLKS + MASK_BLKS, 256, 0, stream>>>(
            y16, row_ptr, csr, aggF, mk, mk0, mk1);
        int mode = (l < 2) ? 0 : 1;
        gemm_kernel<<<1264, 256, 0, stream>>>(
            aggF, Wt + (size_t)l * 512 * 512, bl[l], rn_in,
            y16, out, mode, maskbuf);
    }
}